// Round 17
// baseline (783.649 us; speedup 1.0000x reference)
//
#include <hip/hip_runtime.h>
#include <hip/hip_bf16.h>

// Problem dims (fixed by reference): x[B*S=8192, E=2048], w1/w2[H=8192, E], w3[E, H]
#define M_ROWS 8192
#define E_DIM  2048
#define H_DIM  8192

typedef __attribute__((ext_vector_type(8))) short bf16x8;
typedef __attribute__((ext_vector_type(4))) float f32x4;
typedef __attribute__((ext_vector_type(4))) unsigned int uint4v;

__device__ __forceinline__ unsigned short f2bf_rne(float x) {
  unsigned u = __builtin_bit_cast(unsigned, x);
  u += 0x7FFFu + ((u >> 16) & 1u);
  return (unsigned short)(u >> 16);
}

// ---------------- fp32 -> bf16 conversion, up to 4 segments per launch ----------------
__global__ __launch_bounds__(256) void cvt4_f32_bf16(const float* __restrict__ s0, unsigned short* __restrict__ d0,
                                                     const float* __restrict__ s1, unsigned short* __restrict__ d1,
                                                     const float* __restrict__ s2, unsigned short* __restrict__ d2,
                                                     const float* __restrict__ s3, unsigned short* __restrict__ d3,
                                                     int n8) {
  int i = blockIdx.x * blockDim.x + threadIdx.x;
  if (i >= n8) return;
  const float* in = (blockIdx.y == 0) ? s0 : (blockIdx.y == 1) ? s1 : (blockIdx.y == 2) ? s2 : s3;
  unsigned short* out = (blockIdx.y == 0) ? d0 : (blockIdx.y == 1) ? d1 : (blockIdx.y == 2) ? d2 : d3;
  const float4* p = (const float4*)(in + (size_t)i * 8);
  float4 a = p[0];
  float4 b = p[1];
  union { unsigned short us[8]; uint4v v; } r;
  r.us[0] = f2bf_rne(a.x); r.us[1] = f2bf_rne(a.y);
  r.us[2] = f2bf_rne(a.z); r.us[3] = f2bf_rne(a.w);
  r.us[4] = f2bf_rne(b.x); r.us[5] = f2bf_rne(b.y);
  r.us[6] = f2bf_rne(b.z); r.us[7] = f2bf_rne(b.w);
  *(uint4v*)(out + (size_t)i * 8) = r.v;
}

// ---------------- async global -> LDS, 16B per lane ----------------
__device__ __forceinline__ void gld_lds16(const unsigned short* g, unsigned short* l) {
  __builtin_amdgcn_global_load_lds(
      (const __attribute__((address_space(1))) unsigned int*)g,
      (__attribute__((address_space(3))) unsigned int*)l, 16, 0, 0);
}

#define VMCNT(n)   asm volatile("s_waitcnt vmcnt(" #n ")" ::: "memory")

// ====== 256-row 8-phase/2-K-tile GEMM (m201 cadence; R16 skeleton + PERSISTENT SWEEP) ======
// 512 threads, BK=64, buf0=even buf1=odd K-tiles, 128KiB flat LDS, XOR-swizzled LDS
// reads via pre-swizzled global source, setprio on MFMA, vmcnt(6) at ph4/ph8, lgkm(8)
// hint on 12-read phases. Per-phase stage cadence + WAR/vmcnt ledger IDENTICAL to R12
// (stage DESTS and TIMING unchanged; only stage SOURCES roll across output tiles).
// PERSISTENT SWEEP (NSUB output tiles per block): the K-loop tail's (t+2),(t+3)>=NT
// stages redirect to the NEXT output tile's K-tiles 0,1 (offset = (t+.)mod NT; B
// pointers switch to next panel; A is sub-invariant). Prologue = 7 stageH + vmcnt(6)
// (tile1.A.H1 moved to it0-ph1; induction verified identical). Epilogue stores sit in
// the vmcnt queue as OLDER entries -> counted waits only get stricter. One prologue
// drain per block instead of NSUB.
// EPI=0 (down-proj): 8 waves 2Mx4N, 256x256 tile, fp32 store, generic XCD swizzle,
//   NSUB=1 (grid is already 1 block/CU).
// EPI=3 (fused gate+up): 8 waves 4Mx2N, each wave computes gate (acc[0-3], w1=B-LDS
//   H0) and up (acc[4-7], w2=H1) for the same 64x64 sub-tile; wave-local silu epilogue
//   (R16-verified). Grid 256 (1/CU); block sweeps its XCD's 8 bcol panels (NSUB=8).
template <int EPI>
__global__ __launch_bounds__(512, 2)
void gemm256(const unsigned short* __restrict__ A,
             const unsigned short* __restrict__ B,
             const unsigned short* __restrict__ B2,
             void* __restrict__ Cout,
             int M, int N, int K) {
  __shared__ unsigned short sh[65536];     // 128KiB: [0,32768)=lA dbuf, [32768,65536)=lB dbuf
  unsigned short* lAb = sh;                // lA[parity] = lAb + parity*16384
  unsigned short* lBb = sh + 32768;        // lB[parity] = lBb + parity*16384

  const int tid = threadIdx.x;
  const int lane = tid & 63;
  const int wave = tid >> 6;
  const int wr = wave >> 2;   // EPI0: 0..1 (128 rows each)
  const int wc = wave & 3;    // EPI0: 0..3 (64 cols each)
  const int wrow = wave >> 1; // EPI3: 0..3 (64 rows each)
  const int wcol = wave & 1;  // EPI3: 0..1 (64 cols each)
  const int lr = lane & 15, lk = lane >> 4;

  const int gx = gridDim.x;
  const int wg = blockIdx.y * gx + blockIdx.x;
  const int NSUB = (EPI == 3) ? 8 : 1;
  int bcol0, brow;
  if constexpr (EPI == 3) {
    // persistent: block = (xcd, brow); sweeps bcol = xcd*8 + sub, sub=0..7
    const int xcd = wg & 7;
    brow = wg >> 3;
    bcol0 = xcd * 8;
  } else {
    // generic bijective XCD swizzle (nwg % 8 == 0)
    const int nwg = gx * gridDim.y;
    const int swz = (wg & 7) * (nwg >> 3) + (wg >> 3);
    bcol0 = swz % gx;
    brow = swz / gx;
  }

  const unsigned short* Ag = A + (size_t)brow * 256 * K;
  const unsigned short* AgH1 = Ag + (size_t)128 * K;

  auto panelH0 = [&](int bc) {
    return (EPI == 3) ? B + (size_t)bc * 128 * K : B + (size_t)bc * 256 * K;
  };
  auto panelH1 = [&](int bc) {
    return (EPI == 3) ? B2 + (size_t)bc * 128 * K : B + (size_t)bc * 256 * K + (size_t)128 * K;
  };

  f32x4 acc[8][4] = {};
  const int NT = K >> 6;        // 32 (fused) / 128 (down); power of 2
  const int NI = NT >> 1;
  const int NTm = NT - 1;

  // stage one 128x64 half-tile: linear LDS dest (lane*16B), inverse-swizzled global src
  auto stageH = [&](const unsigned short* gbase, unsigned short* ldsh) {
#pragma unroll
    for (int i = 0; i < 2; ++i) {
      int p = i * 4096 + tid * 8;               // physical element offset in half
      int row = p >> 6;                          // 0..127
      int lslot = ((p >> 3) & 7) ^ (row & 7);    // logical 8-elem slot
      gld_lds16(gbase + (size_t)row * K + lslot * 8, ldsh + p);
    }
  };

  const int xsw = (lr & 7) << 3;  // read-side swizzle XOR (element units)
  bf16x8 af[8][2], bf[4][2], bu[4][2];  // EPI3: af[0-3], bf=w1 frags, bu=w2 frags

#define RD_PH1(LA, LB) \
  if constexpr (EPI == 3) { \
    _Pragma("unroll") for (int m = 0; m < 4; ++m) { \
      int r = wrow * 64 + m * 16 + lr; \
      af[m][0] = *(const bf16x8*)&LA[(r * 64 + lk * 8) ^ xsw]; \
      af[m][1] = *(const bf16x8*)&LA[(r * 64 + 32 + lk * 8) ^ xsw]; } \
    _Pragma("unroll") for (int n = 0; n < 2; ++n) { \
      int r = wcol * 64 + n * 16 + lr; \
      bf[n][0] = *(const bf16x8*)&LB[(r * 64 + lk * 8) ^ xsw]; \
      bf[n][1] = *(const bf16x8*)&LB[(r * 64 + 32 + lk * 8) ^ xsw]; } \
  } else { \
    _Pragma("unroll") for (int m = 0; m < 4; ++m) { \
      int r = wr * 128 + m * 16 + lr; \
      af[m][0] = *(const bf16x8*)&LA[(r * 64 + lk * 8) ^ xsw]; \
      af[m][1] = *(const bf16x8*)&LA[(r * 64 + 32 + lk * 8) ^ xsw]; } \
    _Pragma("unroll") for (int n = 0; n < 2; ++n) { \
      int r = wc * 64 + n * 16 + lr; \
      bf[n][0] = *(const bf16x8*)&LB[(r * 64 + lk * 8) ^ xsw]; \
      bf[n][1] = *(const bf16x8*)&LB[(r * 64 + 32 + lk * 8) ^ xsw]; } \
  }
#define RD_PH2(LB) \
  { \
    const int wcx = (EPI == 3) ? wcol : wc; \
    _Pragma("unroll") for (int n = 2; n < 4; ++n) { \
      int r = wcx * 64 + n * 16 + lr; \
      bf[n][0] = *(const bf16x8*)&LB[(r * 64 + lk * 8) ^ xsw]; \
      bf[n][1] = *(const bf16x8*)&LB[(r * 64 + 32 + lk * 8) ^ xsw]; } \
  }
#define RD_PH3(LA, LB) \
  if constexpr (EPI == 3) { \
    _Pragma("unroll") for (int n = 0; n < 4; ++n) { \
      int r = wcol * 64 + n * 16 + lr; \
      bu[n][0] = *(const bf16x8*)&LB[8192 + ((r * 64 + lk * 8) ^ xsw)]; \
      bu[n][1] = *(const bf16x8*)&LB[8192 + ((r * 64 + 32 + lk * 8) ^ xsw)]; } \
  } else { \
    _Pragma("unroll") for (int m = 4; m < 8; ++m) { \
      int r = wr * 128 + m * 16 + lr; \
      af[m][0] = *(const bf16x8*)&LA[(r * 64 + lk * 8) ^ xsw]; \
      af[m][1] = *(const bf16x8*)&LA[(r * 64 + 32 + lk * 8) ^ xsw]; } \
  }
#define PH_CORE_BEGIN \
  __builtin_amdgcn_s_barrier(); \
  asm volatile("s_waitcnt lgkmcnt(0)" ::: "memory"); \
  __builtin_amdgcn_sched_barrier(0); \
  __builtin_amdgcn_s_setprio(1);
#define PH_CORE_END __builtin_amdgcn_s_setprio(0);
#define MF(ACC_M, AV, BV) \
  acc[ACC_M][n] = __builtin_amdgcn_mfma_f32_16x16x32_bf16(AV[ks], BV[ks], acc[ACC_M][n], 0, 0, 0);
#define PH_MFMA_Q(Q) \
  PH_CORE_BEGIN \
  if constexpr (EPI == 3) { \
    if constexpr (Q == 1) { _Pragma("unroll") for (int m = 0; m < 4; ++m) _Pragma("unroll") for (int n = 0; n < 2; ++n) _Pragma("unroll") for (int ks = 0; ks < 2; ++ks) MF(m, af[m], bf[n]) } \
    if constexpr (Q == 2) { _Pragma("unroll") for (int m = 0; m < 4; ++m) _Pragma("unroll") for (int n = 2; n < 4; ++n) _Pragma("unroll") for (int ks = 0; ks < 2; ++ks) MF(m, af[m], bf[n]) } \
    if constexpr (Q == 3) { _Pragma("unroll") for (int m = 0; m < 4; ++m) _Pragma("unroll") for (int n = 0; n < 2; ++n) _Pragma("unroll") for (int ks = 0; ks < 2; ++ks) MF(m + 4, af[m], bu[n]) } \
    if constexpr (Q == 4) { _Pragma("unroll") for (int m = 0; m < 4; ++m) _Pragma("unroll") for (int n = 2; n < 4; ++n) _Pragma("unroll") for (int ks = 0; ks < 2; ++ks) MF(m + 4, af[m], bu[n]) } \
  } else { \
    if constexpr (Q == 1) { _Pragma("unroll") for (int m = 0; m < 4; ++m) _Pragma("unroll") for (int n = 0; n < 2; ++n) _Pragma("unroll") for (int ks = 0; ks < 2; ++ks) MF(m, af[m], bf[n]) } \
    if constexpr (Q == 2) { _Pragma("unroll") for (int m = 0; m < 4; ++m) _Pragma("unroll") for (int n = 2; n < 4; ++n) _Pragma("unroll") for (int ks = 0; ks < 2; ++ks) MF(m, af[m], bf[n]) } \
    if constexpr (Q == 3) { _Pragma("unroll") for (int m = 4; m < 8; ++m) _Pragma("unroll") for (int n = 0; n < 2; ++n) _Pragma("unroll") for (int ks = 0; ks < 2; ++ks) MF(m, af[m], bf[n]) } \
    if constexpr (Q == 4) { _Pragma("unroll") for (int m = 4; m < 8; ++m) _Pragma("unroll") for (int n = 2; n < 4; ++n) _Pragma("unroll") for (int ks = 0; ks < 2; ++ks) MF(m, af[m], bf[n]) } \
  } \
  PH_CORE_END

  // ---- prologue: tile0 {A.H0,A.H1,B.H0,B.H1} + tile1 {A.H0,B.H0,B.H1}; vmcnt(6) ----
  // (tile1.A.H1 is staged at it0-ph1 — induction identical to R12's steady state)
  {
    const unsigned short* P0 = panelH0(bcol0);
    const unsigned short* P1 = panelH1(bcol0);
    stageH(Ag, lAb);
    stageH(AgH1, lAb + 8192);
    stageH(P0, lBb);
    stageH(P1, lBb + 8192);
    stageH(Ag + 64, lAb + 16384);
    stageH(P0 + 64, lBb + 16384);
    stageH(P1 + 64, lBb + 16384 + 8192);
  }
  VMCNT(6);   // tile0's 8 loads retired; tile1's 3 stageH (6 loads) in flight
  __builtin_amdgcn_s_barrier();

  const unsigned short* lA0 = lAb;
  const unsigned short* lB0 = lBb;
  const unsigned short* lA1 = lAb + 16384;
  const unsigned short* lB1 = lBb + 16384;

  for (int sub = 0; sub < NSUB; ++sub) {
    const int bcol = bcol0 + sub;
    const unsigned short* BgH0 = panelH0(bcol);
    const unsigned short* BgH1 = panelH1(bcol);
    const int nsub = (sub + 1 < NSUB) ? sub + 1 : sub;  // last sub: self (unread data)
    const unsigned short* BgH0n = panelH0(bcol0 + nsub);
    const unsigned short* BgH1n = panelH1(bcol0 + nsub);

    for (int it = 0; it < NI; ++it) {
      const int t = it << 1;
      const size_t kT1 = (size_t)(t + 1) * 64;
      const bool o2 = (t + 2 >= NT);
      const bool o3 = (t + 3 >= NT);
      const size_t k2 = (size_t)((t + 2) & NTm) * 64;
      const size_t k3 = (size_t)((t + 3) & NTm) * 64;
      const unsigned short* B0s2 = (o2 ? BgH0n : BgH0) + k2;
      const unsigned short* B1s2 = (o2 ? BgH1n : BgH1) + k2;
      const unsigned short* B0s3 = (o3 ? BgH0n : BgH0) + k3;
      const unsigned short* B1s3 = (o3 ? BgH1n : BgH1) + k3;

      // ---- ph1: rd (12) | stage A.H1(t+1) | lgkm(8) | Q1
      RD_PH1(lA0, lB0);
      stageH(AgH1 + kT1, lAb + 16384 + 8192);
      asm volatile("s_waitcnt lgkmcnt(8)" ::: "memory");
      PH_MFMA_Q(1);
      __builtin_amdgcn_s_barrier();

      // ---- ph2: rd (4) | Q2
      RD_PH2(lB0);
      PH_MFMA_Q(2);
      __builtin_amdgcn_s_barrier();

      // ---- ph3: rd (8) | stage B.H0(t+2) | Q3
      RD_PH3(lA0, lB0);
      stageH(B0s2, lBb);
      PH_MFMA_Q(3);
      __builtin_amdgcn_s_barrier();

      // ---- ph4: stage B.H1(t+2), A.H0(t+2) | Q4 | vmcnt(6)
      stageH(B1s2, lBb + 8192);
      stageH(Ag + k2, lAb);
      PH_MFMA_Q(4);
      VMCNT(6);
      __builtin_amdgcn_s_barrier();

      // ---- ph5: rd t+1 (12) | stage A.H1(t+2) | lgkm(8) | Q1
      RD_PH1(lA1, lB1);
      stageH(AgH1 + k2, lAb + 8192);
      asm volatile("s_waitcnt lgkmcnt(8)" ::: "memory");
      PH_MFMA_Q(1);
      __builtin_amdgcn_s_barrier();

      // ---- ph6: rd t+1 (4) | Q2
      RD_PH2(lB1);
      PH_MFMA_Q(2);
      __builtin_amdgcn_s_barrier();

      // ---- ph7: rd t+1 (8) | stage B.H0(t+3) | Q3
      RD_PH3(lA1, lB1);
      stageH(B0s3, lBb + 16384);
      PH_MFMA_Q(3);
      __builtin_amdgcn_s_barrier();

      // ---- ph8: stage B.H1(t+3), A.H0(t+3) | Q4 | vmcnt(6)
      stageH(B1s3, lBb + 16384 + 8192);
      stageH(Ag + k3, lAb + 16384);
      PH_MFMA_Q(4);
      VMCNT(6);
      __builtin_amdgcn_s_barrier();
    }

    // ---- per-sub epilogue (no LDS, no barriers; stores age into vmcnt queue as
    //      OLDER entries -> later counted waits only get stricter) ----
    if constexpr (EPI == 3) {
      const int row0 = brow * 256 + wrow * 64 + lk * 4;
      const int col0 = bcol * 128 + wcol * 64 + lr;
#pragma unroll
      for (int m = 0; m < 4; ++m)
#pragma unroll
        for (int n = 0; n < 4; ++n)
#pragma unroll
          for (int j = 0; j < 4; ++j) {
            float g = acc[m][n][j];       // gate
            float u = acc[m + 4][n][j];   // up
            float s = g / (1.0f + __expf(-g));  // silu
            ((unsigned short*)Cout)[(size_t)(row0 + m * 16 + j) * N + (col0 + n * 16)] =
                f2bf_rne(s * u);
          }
      if (sub + 1 < NSUB) {
#pragma unroll
        for (int m = 0; m < 8; ++m)
#pragma unroll
          for (int n = 0; n < 4; ++n)
            acc[m][n] = f32x4{0.f, 0.f, 0.f, 0.f};
      }
    } else {
      const int row0 = brow * 256 + wr * 128 + lk * 4;
      const int col0 = bcol * 256 + wc * 64 + lr;
#pragma unroll
      for (int m = 0; m < 8; ++m)
#pragma unroll
        for (int n = 0; n < 4; ++n)
#pragma unroll
          for (int j = 0; j < 4; ++j) {
            size_t idx = (size_t)(row0 + m * 16 + j) * N + (col0 + n * 16);
            ((float*)Cout)[idx] = acc[m][n][j];
          }
    }
  }
  VMCNT(0);  // drain trailing (unread) tail stages before exit

#undef RD_PH1
#undef RD_PH2
#undef RD_PH3
#undef PH_CORE_BEGIN
#undef PH_CORE_END
#undef MF
#undef PH_MFMA_Q
}

extern "C" void kernel_launch(void* const* d_in, const int* in_sizes, int n_in,
                              void* d_out, int out_size, void* d_ws, size_t ws_size,
                              hipStream_t stream) {
  const float* x  = (const float*)d_in[0];
  const float* w1 = (const float*)d_in[1];
  const float* w2 = (const float*)d_in[2];
  const float* w3 = (const float*)d_in[3];
  float* out = (float*)d_out;

  const int M = M_ROWS, E = E_DIM, H = H_DIM;

  // ws layout (bf16 elements):
  //   [0, 32MB)   xb    | [32, 64MB) w1b | [64, 96MB) w2b | [96, 224MB) h
  //   w3b: [224, 256MB) if ws_size permits (hoisted cvt), else aliases xb (late cvt).
  unsigned short* xb  = (unsigned short*)d_ws;
  unsigned short* w1b = xb + (size_t)M * E;
  unsigned short* w2b = w1b + (size_t)H * E;
  unsigned short* hb  = w2b + (size_t)H * E;

  const int n8 = (M * E) / 8;  // == (H*E)/8 == (E*H)/8 == 2097152
  const size_t need_hoist = ((size_t)M * E + 2 * (size_t)H * E + (size_t)M * H + (size_t)E * H) * 2;

  if (ws_size >= need_hoist) {
    unsigned short* w3b = hb + (size_t)M * H;  // dedicated region
    cvt4_f32_bf16<<<dim3(n8 / 256, 4), 256, 0, stream>>>(x, xb, w1, w1b, w2, w2b, w3, w3b, n8);
    gemm256<3><<<dim3(256), 512, 0, stream>>>(xb, w1b, w2b, hb, M, H, E);
    gemm256<0><<<dim3(E / 256, M / 256), 512, 0, stream>>>(hb, w3b, nullptr, out, M, E, H);
  } else {
    unsigned short* w3b = xb;  // safe: cvt(w3) is stream-ordered after fused GEMM reads xb
    cvt4_f32_bf16<<<dim3(n8 / 256, 3), 256, 0, stream>>>(x, xb, w1, w1b, w2, w2b, nullptr, nullptr, n8);
    gemm256<3><<<dim3(256), 512, 0, stream>>>(xb, w1b, w2b, hb, M, H, E);
    cvt4_f32_bf16<<<dim3(n8 / 256, 1), 256, 0, stream>>>(w3, w3b, nullptr, nullptr, nullptr, nullptr, nullptr, nullptr, n8);
    gemm256<0><<<dim3(E / 256, M / 256), 512, 0, stream>>>(hb, w3b, nullptr, out, M, E, H);
  }
}

// Round 18
// 776.422 us; speedup vs baseline: 1.0093x; 1.0093x over previous
//
#include <hip/hip_runtime.h>
#include <hip/hip_bf16.h>

// Problem dims (fixed by reference): x[B*S=8192, E=2048], w1/w2[H=8192, E], w3[E, H]
#define M_ROWS 8192
#define E_DIM  2048
#define H_DIM  8192

typedef __attribute__((ext_vector_type(8))) short bf16x8;
typedef __attribute__((ext_vector_type(4))) float f32x4;
typedef __attribute__((ext_vector_type(4))) unsigned int uint4v;

__device__ __forceinline__ unsigned short f2bf_rne(float x) {
  unsigned u = __builtin_bit_cast(unsigned, x);
  u += 0x7FFFu + ((u >> 16) & 1u);
  return (unsigned short)(u >> 16);
}

// ---------------- fp32 -> bf16 conversion, up to 4 segments per launch ----------------
__global__ __launch_bounds__(256) void cvt4_f32_bf16(const float* __restrict__ s0, unsigned short* __restrict__ d0,
                                                     const float* __restrict__ s1, unsigned short* __restrict__ d1,
                                                     const float* __restrict__ s2, unsigned short* __restrict__ d2,
                                                     const float* __restrict__ s3, unsigned short* __restrict__ d3,
                                                     int n8) {
  int i = blockIdx.x * blockDim.x + threadIdx.x;
  if (i >= n8) return;
  const float* in = (blockIdx.y == 0) ? s0 : (blockIdx.y == 1) ? s1 : (blockIdx.y == 2) ? s2 : s3;
  unsigned short* out = (blockIdx.y == 0) ? d0 : (blockIdx.y == 1) ? d1 : (blockIdx.y == 2) ? d2 : d3;
  const float4* p = (const float4*)(in + (size_t)i * 8);
  float4 a = p[0];
  float4 b = p[1];
  union { unsigned short us[8]; uint4v v; } r;
  r.us[0] = f2bf_rne(a.x); r.us[1] = f2bf_rne(a.y);
  r.us[2] = f2bf_rne(a.z); r.us[3] = f2bf_rne(a.w);
  r.us[4] = f2bf_rne(b.x); r.us[5] = f2bf_rne(b.y);
  r.us[6] = f2bf_rne(b.z); r.us[7] = f2bf_rne(b.w);
  *(uint4v*)(out + (size_t)i * 8) = r.v;
}

// ---------------- async global -> LDS, 16B per lane ----------------
__device__ __forceinline__ void gld_lds16(const unsigned short* g, unsigned short* l) {
  __builtin_amdgcn_global_load_lds(
      (const __attribute__((address_space(1))) unsigned int*)g,
      (__attribute__((address_space(3))) unsigned int*)l, 16, 0, 0);
}

#define VMCNT(n)   asm volatile("s_waitcnt vmcnt(" #n ")" ::: "memory")

// =============== 256-row 8-phase/2-K-tile GEMM (m201 cadence; R16 config EXACT) ===============
// 512 threads, BK=64, buf0=even buf1=odd K-tiles, 128KiB flat LDS, XOR-swizzled LDS
// reads via pre-swizzled global source, setprio on MFMA, vmcnt(6) at ph4/ph8, lgkm(8)
// hint on 12-read phases. Stage cadence + vmcnt ledger = R12-verified schedule.
// EPI=0 (down-proj): 8 waves 2Mx4N, 256x256 tile, fp32 store, generic XCD swizzle.
// EPI=3 (fused gate+up): 8 waves 4Mx2N — each wave computes BOTH gate (acc[0-3], vs
//   w1 in B-LDS H0) and up (acc[4-7], vs w2 in H1) for the SAME 64x64 sub-tile;
//   wave-local silu(g)*u epilogue (R16-verified: MfmaUtil 47, WRITE 164MB).
//   XCD column-chunking (R12-verified: FETCH 1.13->0.44GB).
//   [R17's persistent sweep reverted: FETCH tripled (A-panel L2 thrash), dur flat.]
template <int EPI>
__global__ __launch_bounds__(512, 2)
void gemm256(const unsigned short* __restrict__ A,
             const unsigned short* __restrict__ B,
             const unsigned short* __restrict__ B2,
             void* __restrict__ Cout,
             int M, int N, int K) {
  __shared__ unsigned short sh[65536];     // 128KiB: [0,32768)=lA dbuf, [32768,65536)=lB dbuf
  unsigned short* lAb = sh;                // lA[parity] = lAb + parity*16384
  unsigned short* lBb = sh + 32768;        // lB[parity] = lBb + parity*16384

  const int tid = threadIdx.x;
  const int lane = tid & 63;
  const int wave = tid >> 6;
  const int wr = wave >> 2;   // EPI0: 0..1 (128 rows each)
  const int wc = wave & 3;    // EPI0: 0..3 (64 cols each)
  const int wrow = wave >> 1; // EPI3: 0..3 (64 rows each)
  const int wcol = wave & 1;  // EPI3: 0..1 (64 cols each)
  const int lr = lane & 15, lk = lane >> 4;

  const int gx = gridDim.x;
  const int wg = blockIdx.y * gx + blockIdx.x;
  int bcol, brow;
  if constexpr (EPI == 3) {
    // XCD column-chunking (bijective: wg = (brow*8 + (bcol&7))*8 + (bcol>>3))
    const int xcd = wg & 7, idx = wg >> 3;
    bcol = xcd * 8 + (idx & 7);
    brow = idx >> 3;
  } else {
    // generic bijective XCD swizzle (nwg % 8 == 0)
    const int nwg = gx * gridDim.y;
    const int swz = (wg & 7) * (nwg >> 3) + (wg >> 3);
    bcol = swz % gx;
    brow = swz / gx;
  }

  const unsigned short* Ag = A + (size_t)brow * 256 * K;
  const unsigned short* BgH0;  // source for B-LDS rows 0-127
  const unsigned short* BgH1;  // source for B-LDS rows 128-255
  if constexpr (EPI == 3) {
    BgH0 = B  + (size_t)bcol * 128 * K;   // w1 panel
    BgH1 = B2 + (size_t)bcol * 128 * K;   // w2 panel
  } else {
    BgH0 = B + (size_t)bcol * 256 * K;
    BgH1 = BgH0 + (size_t)128 * K;
  }

  f32x4 acc[8][4] = {};
  const int NT = K >> 6;
  const int NI = NT >> 1;

  // stage one 128x64 half-tile: linear LDS dest (lane*16B), inverse-swizzled global src
  auto stageH = [&](const unsigned short* gbase, unsigned short* ldsh) {
#pragma unroll
    for (int i = 0; i < 2; ++i) {
      int p = i * 4096 + tid * 8;               // physical element offset in half
      int row = p >> 6;                          // 0..127
      int lslot = ((p >> 3) & 7) ^ (row & 7);    // logical 8-elem slot
      gld_lds16(gbase + (size_t)row * K + lslot * 8, ldsh + p);
    }
  };

  const int xsw = (lr & 7) << 3;  // read-side swizzle XOR (element units)
  bf16x8 af[8][2], bf[4][2], bu[4][2];  // EPI3: af[0-3], bf=w1 frags, bu=w2 frags

  // ---- phase read helpers ----
#define RD_PH1(LA, LB) \
  if constexpr (EPI == 3) { \
    _Pragma("unroll") for (int m = 0; m < 4; ++m) { \
      int r = wrow * 64 + m * 16 + lr; \
      af[m][0] = *(const bf16x8*)&LA[(r * 64 + lk * 8) ^ xsw]; \
      af[m][1] = *(const bf16x8*)&LA[(r * 64 + 32 + lk * 8) ^ xsw]; } \
    _Pragma("unroll") for (int n = 0; n < 2; ++n) { \
      int r = wcol * 64 + n * 16 + lr; \
      bf[n][0] = *(const bf16x8*)&LB[(r * 64 + lk * 8) ^ xsw]; \
      bf[n][1] = *(const bf16x8*)&LB[(r * 64 + 32 + lk * 8) ^ xsw]; } \
  } else { \
    _Pragma("unroll") for (int m = 0; m < 4; ++m) { \
      int r = wr * 128 + m * 16 + lr; \
      af[m][0] = *(const bf16x8*)&LA[(r * 64 + lk * 8) ^ xsw]; \
      af[m][1] = *(const bf16x8*)&LA[(r * 64 + 32 + lk * 8) ^ xsw]; } \
    _Pragma("unroll") for (int n = 0; n < 2; ++n) { \
      int r = wc * 64 + n * 16 + lr; \
      bf[n][0] = *(const bf16x8*)&LB[(r * 64 + lk * 8) ^ xsw]; \
      bf[n][1] = *(const bf16x8*)&LB[(r * 64 + 32 + lk * 8) ^ xsw]; } \
  }
#define RD_PH2(LB) \
  { \
    const int wcx = (EPI == 3) ? wcol : wc; \
    _Pragma("unroll") for (int n = 2; n < 4; ++n) { \
      int r = wcx * 64 + n * 16 + lr; \
      bf[n][0] = *(const bf16x8*)&LB[(r * 64 + lk * 8) ^ xsw]; \
      bf[n][1] = *(const bf16x8*)&LB[(r * 64 + 32 + lk * 8) ^ xsw]; } \
  }
#define RD_PH3(LA, LB) \
  if constexpr (EPI == 3) { \
    _Pragma("unroll") for (int n = 0; n < 4; ++n) { \
      int r = wcol * 64 + n * 16 + lr; \
      bu[n][0] = *(const bf16x8*)&LB[8192 + ((r * 64 + lk * 8) ^ xsw)]; \
      bu[n][1] = *(const bf16x8*)&LB[8192 + ((r * 64 + 32 + lk * 8) ^ xsw)]; } \
  } else { \
    _Pragma("unroll") for (int m = 4; m < 8; ++m) { \
      int r = wr * 128 + m * 16 + lr; \
      af[m][0] = *(const bf16x8*)&LA[(r * 64 + lk * 8) ^ xsw]; \
      af[m][1] = *(const bf16x8*)&LA[(r * 64 + 32 + lk * 8) ^ xsw]; } \
  }
  // ---- phase MFMA helpers (Q = quadrant index 1..4) ----
#define PH_CORE_BEGIN \
  __builtin_amdgcn_s_barrier(); \
  asm volatile("s_waitcnt lgkmcnt(0)" ::: "memory"); \
  __builtin_amdgcn_sched_barrier(0); \
  __builtin_amdgcn_s_setprio(1);
#define PH_CORE_END __builtin_amdgcn_s_setprio(0);
#define MF(ACC_M, AV, BV) \
  acc[ACC_M][n] = __builtin_amdgcn_mfma_f32_16x16x32_bf16(AV[ks], BV[ks], acc[ACC_M][n], 0, 0, 0);
#define PH_MFMA_Q(Q) \
  PH_CORE_BEGIN \
  if constexpr (EPI == 3) { \
    if constexpr (Q == 1) { _Pragma("unroll") for (int m = 0; m < 4; ++m) _Pragma("unroll") for (int n = 0; n < 2; ++n) _Pragma("unroll") for (int ks = 0; ks < 2; ++ks) MF(m, af[m], bf[n]) } \
    if constexpr (Q == 2) { _Pragma("unroll") for (int m = 0; m < 4; ++m) _Pragma("unroll") for (int n = 2; n < 4; ++n) _Pragma("unroll") for (int ks = 0; ks < 2; ++ks) MF(m, af[m], bf[n]) } \
    if constexpr (Q == 3) { _Pragma("unroll") for (int m = 0; m < 4; ++m) _Pragma("unroll") for (int n = 0; n < 2; ++n) _Pragma("unroll") for (int ks = 0; ks < 2; ++ks) MF(m + 4, af[m], bu[n]) } \
    if constexpr (Q == 4) { _Pragma("unroll") for (int m = 0; m < 4; ++m) _Pragma("unroll") for (int n = 2; n < 4; ++n) _Pragma("unroll") for (int ks = 0; ks < 2; ++ks) MF(m + 4, af[m], bu[n]) } \
  } else { \
    if constexpr (Q == 1) { _Pragma("unroll") for (int m = 0; m < 4; ++m) _Pragma("unroll") for (int n = 0; n < 2; ++n) _Pragma("unroll") for (int ks = 0; ks < 2; ++ks) MF(m, af[m], bf[n]) } \
    if constexpr (Q == 2) { _Pragma("unroll") for (int m = 0; m < 4; ++m) _Pragma("unroll") for (int n = 2; n < 4; ++n) _Pragma("unroll") for (int ks = 0; ks < 2; ++ks) MF(m, af[m], bf[n]) } \
    if constexpr (Q == 3) { _Pragma("unroll") for (int m = 4; m < 8; ++m) _Pragma("unroll") for (int n = 0; n < 2; ++n) _Pragma("unroll") for (int ks = 0; ks < 2; ++ks) MF(m, af[m], bf[n]) } \
    if constexpr (Q == 4) { _Pragma("unroll") for (int m = 4; m < 8; ++m) _Pragma("unroll") for (int n = 2; n < 4; ++n) _Pragma("unroll") for (int ks = 0; ks < 2; ++ks) MF(m, af[m], bf[n]) } \
  } \
  PH_CORE_END

  // ---------------- prologue: stage tiles 0 and 1 fully; drain; barrier ----------------
  stageH(Ag, lAb);
  stageH(Ag + (size_t)128 * K, lAb + 8192);
  stageH(BgH0, lBb);
  stageH(BgH1, lBb + 8192);
  stageH(Ag + 64, lAb + 16384);
  stageH(Ag + (size_t)128 * K + 64, lAb + 16384 + 8192);
  stageH(BgH0 + 64, lBb + 16384);
  stageH(BgH1 + 64, lBb + 16384 + 8192);
  VMCNT(0);
  __builtin_amdgcn_s_barrier();

  const unsigned short* lA0 = lAb;
  const unsigned short* lB0 = lBb;
  const unsigned short* lA1 = lAb + 16384;
  const unsigned short* lB1 = lBb + 16384;

  for (int it = 0; it < NI; ++it) {
    const int t = it << 1;
    const size_t kT1 = (size_t)(t + 1) * 64;
    const size_t kS2 = (size_t)((t + 2 < NT) ? t + 2 : NT - 1) * 64;
    const size_t kS3 = (size_t)((t + 3 < NT) ? t + 3 : NT - 1) * 64;

    // ---- ph1: rd (12) | stage A.H1(t+1) | lgkm(8) | Q1
    RD_PH1(lA0, lB0);
    if (it > 0) stageH(Ag + (size_t)128 * K + kT1, lAb + 16384 + 8192);
    asm volatile("s_waitcnt lgkmcnt(8)" ::: "memory");
    PH_MFMA_Q(1);
    __builtin_amdgcn_s_barrier();

    // ---- ph2: rd (4) | Q2
    RD_PH2(lB0);
    PH_MFMA_Q(2);
    __builtin_amdgcn_s_barrier();

    // ---- ph3: rd (8) | stage B.H0(t+2) | Q3
    RD_PH3(lA0, lB0);
    stageH(BgH0 + kS2, lBb);
    PH_MFMA_Q(3);
    __builtin_amdgcn_s_barrier();

    // ---- ph4: stage B.H1(t+2), A.H0(t+2) | Q4 | vmcnt(6)
    stageH(BgH1 + kS2, lBb + 8192);
    stageH(Ag + kS2, lAb);
    PH_MFMA_Q(4);
    VMCNT(6);
    __builtin_amdgcn_s_barrier();

    // ---- ph5: rd t+1 (12) | stage A.H1(t+2) | lgkm(8) | Q1
    RD_PH1(lA1, lB1);
    stageH(Ag + (size_t)128 * K + kS2, lAb + 8192);
    asm volatile("s_waitcnt lgkmcnt(8)" ::: "memory");
    PH_MFMA_Q(1);
    __builtin_amdgcn_s_barrier();

    // ---- ph6: rd t+1 (4) | Q2
    RD_PH2(lB1);
    PH_MFMA_Q(2);
    __builtin_amdgcn_s_barrier();

    // ---- ph7: rd t+1 (8) | stage B.H0(t+3) | Q3
    RD_PH3(lA1, lB1);
    stageH(BgH0 + kS3, lBb + 16384);
    PH_MFMA_Q(3);
    __builtin_amdgcn_s_barrier();

    // ---- ph8: stage B.H1(t+3), A.H0(t+3) | Q4 | vmcnt(6)
    stageH(BgH1 + kS3, lBb + 16384 + 8192);
    stageH(Ag + kS3, lAb + 16384);
    PH_MFMA_Q(4);
    VMCNT(6);
    __builtin_amdgcn_s_barrier();
  }
  VMCNT(0);  // drain tail stages (all waves' LDS writes) before exit

#undef RD_PH1
#undef RD_PH2
#undef RD_PH3
#undef PH_CORE_BEGIN
#undef PH_CORE_END
#undef MF
#undef PH_MFMA_Q

  if constexpr (EPI == 3) {
    // ---------- wave-local fused epilogue: silu(gate)*up, no LDS, no barriers ----------
    const int row0 = brow * 256 + wrow * 64 + lk * 4;
    const int col0 = bcol * 128 + wcol * 64 + lr;
#pragma unroll
    for (int m = 0; m < 4; ++m)
#pragma unroll
      for (int n = 0; n < 4; ++n)
#pragma unroll
        for (int j = 0; j < 4; ++j) {
          float g = acc[m][n][j];       // gate
          float u = acc[m + 4][n][j];   // up
          float s = g / (1.0f + __expf(-g));  // silu
          ((unsigned short*)Cout)[(size_t)(row0 + m * 16 + j) * N + (col0 + n * 16)] =
              f2bf_rne(s * u);
        }
  } else {
    // Epilogue. C/D frag layout (measured, m89/m91): col = lane&15, row = (lane>>4)*4 + j
    const int row0 = brow * 256 + wr * 128 + lk * 4;
    const int col0 = bcol * 256 + wc * 64 + lr;
#pragma unroll
    for (int m = 0; m < 8; ++m)
#pragma unroll
      for (int n = 0; n < 4; ++n)
#pragma unroll
        for (int j = 0; j < 4; ++j) {
          size_t idx = (size_t)(row0 + m * 16 + j) * N + (col0 + n * 16);
          ((float*)Cout)[idx] = acc[m][n][j];
        }
  }
}

extern "C" void kernel_launch(void* const* d_in, const int* in_sizes, int n_in,
                              void* d_out, int out_size, void* d_ws, size_t ws_size,
                              hipStream_t stream) {
  const float* x  = (const float*)d_in[0];
  const float* w1 = (const float*)d_in[1];
  const float* w2 = (const float*)d_in[2];
  const float* w3 = (const float*)d_in[3];
  float* out = (float*)d_out;

  const int M = M_ROWS, E = E_DIM, H = H_DIM;

  // ws layout (bf16 elements):
  //   [0, 32MB)   xb    | [32, 64MB) w1b | [64, 96MB) w2b | [96, 224MB) h
  //   w3b: [224, 256MB) if ws_size permits (hoisted cvt), else aliases xb (late cvt).
  unsigned short* xb  = (unsigned short*)d_ws;
  unsigned short* w1b = xb + (size_t)M * E;
  unsigned short* w2b = w1b + (size_t)H * E;
  unsigned short* hb  = w2b + (size_t)H * E;

  const int n8 = (M * E) / 8;  // == (H*E)/8 == (E*H)/8 == 2097152
  const size_t need_hoist = ((size_t)M * E + 2 * (size_t)H * E + (size_t)M * H + (size_t)E * H) * 2;

  if (ws_size >= need_hoist) {
    unsigned short* w3b = hb + (size_t)M * H;  // dedicated region
    cvt4_f32_bf16<<<dim3(n8 / 256, 4), 256, 0, stream>>>(x, xb, w1, w1b, w2, w2b, w3, w3b, n8);
    gemm256<3><<<dim3(H / 128, M / 256), 512, 0, stream>>>(xb, w1b, w2b, hb, M, H, E);
    gemm256<0><<<dim3(E / 256, M / 256), 512, 0, stream>>>(hb, w3b, nullptr, out, M, E, H);
  } else {
    unsigned short* w3b = xb;  // safe: cvt(w3) is stream-ordered after fused GEMM reads xb
    cvt4_f32_bf16<<<dim3(n8 / 256, 3), 256, 0, stream>>>(x, xb, w1, w1b, w2, w2b, nullptr, nullptr, n8);
    gemm256<3><<<dim3(H / 128, M / 256), 512, 0, stream>>>(xb, w1b, w2b, hb, M, H, E);
    cvt4_f32_bf16<<<dim3(n8 / 256, 1), 256, 0, stream>>>(w3, w3b, nullptr, nullptr, nullptr, nullptr, nullptr, nullptr, n8);
    gemm256<0><<<dim3(E / 256, M / 256), 512, 0, stream>>>(hb, w3b, nullptr, out, M, E, H);
  }
}

// Round 19
// 754.392 us; speedup vs baseline: 1.0388x; 1.0292x over previous
//
#include <hip/hip_runtime.h>
#include <hip/hip_bf16.h>

// Problem dims (fixed by reference): x[B*S=8192, E=2048], w1/w2[H=8192, E], w3[E, H]
#define M_ROWS 8192
#define E_DIM  2048
#define H_DIM  8192

typedef __attribute__((ext_vector_type(8))) short bf16x8;
typedef __attribute__((ext_vector_type(4))) float f32x4;
typedef __attribute__((ext_vector_type(4))) unsigned int uint4v;

__device__ __forceinline__ unsigned short f2bf_rne(float x) {
  unsigned u = __builtin_bit_cast(unsigned, x);
  u += 0x7FFFu + ((u >> 16) & 1u);
  return (unsigned short)(u >> 16);
}

// ---------------- fp32 -> bf16 conversion, up to 4 segments per launch ----------------
__global__ __launch_bounds__(256) void cvt4_f32_bf16(const float* __restrict__ s0, unsigned short* __restrict__ d0,
                                                     const float* __restrict__ s1, unsigned short* __restrict__ d1,
                                                     const float* __restrict__ s2, unsigned short* __restrict__ d2,
                                                     const float* __restrict__ s3, unsigned short* __restrict__ d3,
                                                     int n8) {
  int i = blockIdx.x * blockDim.x + threadIdx.x;
  if (i >= n8) return;
  const float* in = (blockIdx.y == 0) ? s0 : (blockIdx.y == 1) ? s1 : (blockIdx.y == 2) ? s2 : s3;
  unsigned short* out = (blockIdx.y == 0) ? d0 : (blockIdx.y == 1) ? d1 : (blockIdx.y == 2) ? d2 : d3;
  const float4* p = (const float4*)(in + (size_t)i * 8);
  float4 a = p[0];
  float4 b = p[1];
  union { unsigned short us[8]; uint4v v; } r;
  r.us[0] = f2bf_rne(a.x); r.us[1] = f2bf_rne(a.y);
  r.us[2] = f2bf_rne(a.z); r.us[3] = f2bf_rne(a.w);
  r.us[4] = f2bf_rne(b.x); r.us[5] = f2bf_rne(b.y);
  r.us[6] = f2bf_rne(b.z); r.us[7] = f2bf_rne(b.w);
  *(uint4v*)(out + (size_t)i * 8) = r.v;
}

// ---------------- async global -> LDS, 16B per lane ----------------
__device__ __forceinline__ void gld_lds16(const unsigned short* g, unsigned short* l) {
  __builtin_amdgcn_global_load_lds(
      (const __attribute__((address_space(1))) unsigned int*)g,
      (__attribute__((address_space(3))) unsigned int*)l, 16, 0, 0);
}

#define VMCNT(n)   asm volatile("s_waitcnt vmcnt(" #n ")" ::: "memory")

// ====== 256-row 8-phase/2-K-tile GEMM (m201 cadence; R16 schedule + NSUB=2 BROW-SWEEP) ======
// 512 threads, BK=64, buf0=even buf1=odd K-tiles, 128KiB flat LDS, XOR-swizzled LDS
// reads via pre-swizzled global source, setprio on MFMA, vmcnt(6) at ph4/ph8, lgkm(8)
// hint on 12-read phases. Stage dests + timing + vmcnt ledger = R12/R16-verified;
// only stage SOURCES roll across subs (R17-validated mechanism).
// EPI=0 (down-proj): 8 waves 2Mx4N, 256x256 tile, fp32 store, generic XCD swizzle, NSUB=1.
// EPI=3 (fused gate+up): 8 waves 4Mx2N, wave-local silu epilogue (R16: MfmaUtil 47).
//   NSUB=2 BROW-SWEEP: grid 1024; bcol = xcd*8+(idx&7) FIXED per block (B panels
//   reused across subs; tail B-stages wrap k in-panel); brow = (idx>>3)*2+sub (only A
//   sources redirect at sub boundary). Concurrent per-XCD working set == R16's
//   (8 B-panels + ~4 A-panels) — fixes R17's A-diversity L2 thrash (FETCH 3x).
//   Halves round-boundary fill/drain (8 -> 4 rounds/CU).
template <int EPI>
__global__ __launch_bounds__(512, 2)
void gemm256(const unsigned short* __restrict__ A,
             const unsigned short* __restrict__ B,
             const unsigned short* __restrict__ B2,
             void* __restrict__ Cout,
             int M, int N, int K) {
  __shared__ unsigned short sh[65536];     // 128KiB: [0,32768)=lA dbuf, [32768,65536)=lB dbuf
  unsigned short* lAb = sh;                // lA[parity] = lAb + parity*16384
  unsigned short* lBb = sh + 32768;        // lB[parity] = lBb + parity*16384

  const int tid = threadIdx.x;
  const int lane = tid & 63;
  const int wave = tid >> 6;
  const int wr = wave >> 2;   // EPI0: 0..1 (128 rows each)
  const int wc = wave & 3;    // EPI0: 0..3 (64 cols each)
  const int wrow = wave >> 1; // EPI3: 0..3 (64 rows each)
  const int wcol = wave & 1;  // EPI3: 0..1 (64 cols each)
  const int lr = lane & 15, lk = lane >> 4;

  const int gx = gridDim.x;
  const int wg = blockIdx.y * gx + blockIdx.x;
  const int NSUB = (EPI == 3) ? 2 : 1;
  int bcol, brow0;
  if constexpr (EPI == 3) {
    // brow-sweep mapping (bijective over 1024 blocks x 2 subs = 2048 tiles)
    const int xcd = wg & 7, idx = wg >> 3;
    bcol = xcd * 8 + (idx & 7);       // 0..63, FIXED per block
    brow0 = (idx >> 3) * 2;           // block sweeps brow0, brow0+1
  } else {
    // generic bijective XCD swizzle (nwg % 8 == 0)
    const int nwg = gx * gridDim.y;
    const int swz = (wg & 7) * (nwg >> 3) + (wg >> 3);
    bcol = swz % gx;
    brow0 = swz / gx;
  }

  const unsigned short* BgH0;  // source for B-LDS rows 0-127 (fixed per block)
  const unsigned short* BgH1;  // source for B-LDS rows 128-255
  if constexpr (EPI == 3) {
    BgH0 = B  + (size_t)bcol * 128 * K;   // w1 panel
    BgH1 = B2 + (size_t)bcol * 128 * K;   // w2 panel
  } else {
    BgH0 = B + (size_t)bcol * 256 * K;
    BgH1 = BgH0 + (size_t)128 * K;
  }

  f32x4 acc[8][4] = {};
  const int NT = K >> 6;        // 32 (fused) / 128 (down); power of 2
  const int NI = NT >> 1;
  const int NTm = NT - 1;

  // stage one 128x64 half-tile: linear LDS dest (lane*16B), inverse-swizzled global src
  auto stageH = [&](const unsigned short* gbase, unsigned short* ldsh) {
#pragma unroll
    for (int i = 0; i < 2; ++i) {
      int p = i * 4096 + tid * 8;               // physical element offset in half
      int row = p >> 6;                          // 0..127
      int lslot = ((p >> 3) & 7) ^ (row & 7);    // logical 8-elem slot
      gld_lds16(gbase + (size_t)row * K + lslot * 8, ldsh + p);
    }
  };

  const int xsw = (lr & 7) << 3;  // read-side swizzle XOR (element units)
  bf16x8 af[8][2], bf[4][2], bu[4][2];  // EPI3: af[0-3], bf=w1 frags, bu=w2 frags

#define RD_PH1(LA, LB) \
  if constexpr (EPI == 3) { \
    _Pragma("unroll") for (int m = 0; m < 4; ++m) { \
      int r = wrow * 64 + m * 16 + lr; \
      af[m][0] = *(const bf16x8*)&LA[(r * 64 + lk * 8) ^ xsw]; \
      af[m][1] = *(const bf16x8*)&LA[(r * 64 + 32 + lk * 8) ^ xsw]; } \
    _Pragma("unroll") for (int n = 0; n < 2; ++n) { \
      int r = wcol * 64 + n * 16 + lr; \
      bf[n][0] = *(const bf16x8*)&LB[(r * 64 + lk * 8) ^ xsw]; \
      bf[n][1] = *(const bf16x8*)&LB[(r * 64 + 32 + lk * 8) ^ xsw]; } \
  } else { \
    _Pragma("unroll") for (int m = 0; m < 4; ++m) { \
      int r = wr * 128 + m * 16 + lr; \
      af[m][0] = *(const bf16x8*)&LA[(r * 64 + lk * 8) ^ xsw]; \
      af[m][1] = *(const bf16x8*)&LA[(r * 64 + 32 + lk * 8) ^ xsw]; } \
    _Pragma("unroll") for (int n = 0; n < 2; ++n) { \
      int r = wc * 64 + n * 16 + lr; \
      bf[n][0] = *(const bf16x8*)&LB[(r * 64 + lk * 8) ^ xsw]; \
      bf[n][1] = *(const bf16x8*)&LB[(r * 64 + 32 + lk * 8) ^ xsw]; } \
  }
#define RD_PH2(LB) \
  { \
    const int wcx = (EPI == 3) ? wcol : wc; \
    _Pragma("unroll") for (int n = 2; n < 4; ++n) { \
      int r = wcx * 64 + n * 16 + lr; \
      bf[n][0] = *(const bf16x8*)&LB[(r * 64 + lk * 8) ^ xsw]; \
      bf[n][1] = *(const bf16x8*)&LB[(r * 64 + 32 + lk * 8) ^ xsw]; } \
  }
#define RD_PH3(LA, LB) \
  if constexpr (EPI == 3) { \
    _Pragma("unroll") for (int n = 0; n < 4; ++n) { \
      int r = wcol * 64 + n * 16 + lr; \
      bu[n][0] = *(const bf16x8*)&LB[8192 + ((r * 64 + lk * 8) ^ xsw)]; \
      bu[n][1] = *(const bf16x8*)&LB[8192 + ((r * 64 + 32 + lk * 8) ^ xsw)]; } \
  } else { \
    _Pragma("unroll") for (int m = 4; m < 8; ++m) { \
      int r = wr * 128 + m * 16 + lr; \
      af[m][0] = *(const bf16x8*)&LA[(r * 64 + lk * 8) ^ xsw]; \
      af[m][1] = *(const bf16x8*)&LA[(r * 64 + 32 + lk * 8) ^ xsw]; } \
  }
#define PH_CORE_BEGIN \
  __builtin_amdgcn_s_barrier(); \
  asm volatile("s_waitcnt lgkmcnt(0)" ::: "memory"); \
  __builtin_amdgcn_sched_barrier(0); \
  __builtin_amdgcn_s_setprio(1);
#define PH_CORE_END __builtin_amdgcn_s_setprio(0);
#define MF(ACC_M, AV, BV) \
  acc[ACC_M][n] = __builtin_amdgcn_mfma_f32_16x16x32_bf16(AV[ks], BV[ks], acc[ACC_M][n], 0, 0, 0);
#define PH_MFMA_Q(Q) \
  PH_CORE_BEGIN \
  if constexpr (EPI == 3) { \
    if constexpr (Q == 1) { _Pragma("unroll") for (int m = 0; m < 4; ++m) _Pragma("unroll") for (int n = 0; n < 2; ++n) _Pragma("unroll") for (int ks = 0; ks < 2; ++ks) MF(m, af[m], bf[n]) } \
    if constexpr (Q == 2) { _Pragma("unroll") for (int m = 0; m < 4; ++m) _Pragma("unroll") for (int n = 2; n < 4; ++n) _Pragma("unroll") for (int ks = 0; ks < 2; ++ks) MF(m, af[m], bf[n]) } \
    if constexpr (Q == 3) { _Pragma("unroll") for (int m = 0; m < 4; ++m) _Pragma("unroll") for (int n = 0; n < 2; ++n) _Pragma("unroll") for (int ks = 0; ks < 2; ++ks) MF(m + 4, af[m], bu[n]) } \
    if constexpr (Q == 4) { _Pragma("unroll") for (int m = 0; m < 4; ++m) _Pragma("unroll") for (int n = 2; n < 4; ++n) _Pragma("unroll") for (int ks = 0; ks < 2; ++ks) MF(m + 4, af[m], bu[n]) } \
  } else { \
    if constexpr (Q == 1) { _Pragma("unroll") for (int m = 0; m < 4; ++m) _Pragma("unroll") for (int n = 0; n < 2; ++n) _Pragma("unroll") for (int ks = 0; ks < 2; ++ks) MF(m, af[m], bf[n]) } \
    if constexpr (Q == 2) { _Pragma("unroll") for (int m = 0; m < 4; ++m) _Pragma("unroll") for (int n = 2; n < 4; ++n) _Pragma("unroll") for (int ks = 0; ks < 2; ++ks) MF(m, af[m], bf[n]) } \
    if constexpr (Q == 3) { _Pragma("unroll") for (int m = 4; m < 8; ++m) _Pragma("unroll") for (int n = 0; n < 2; ++n) _Pragma("unroll") for (int ks = 0; ks < 2; ++ks) MF(m, af[m], bf[n]) } \
    if constexpr (Q == 4) { _Pragma("unroll") for (int m = 4; m < 8; ++m) _Pragma("unroll") for (int n = 2; n < 4; ++n) _Pragma("unroll") for (int ks = 0; ks < 2; ++ks) MF(m, af[m], bf[n]) } \
  } \
  PH_CORE_END

  // ---- prologue (R17-validated): tile0 {A.H0,A.H1,B.H0,B.H1} + tile1 {A.H0,B.H0,B.H1};
  //      vmcnt(6); tile1.A.H1 staged at it0-ph1 (unconditional) ----
  {
    const unsigned short* Ag0  = A + (size_t)brow0 * 256 * K;
    const unsigned short* Ag0H = Ag0 + (size_t)128 * K;
    stageH(Ag0, lAb);
    stageH(Ag0H, lAb + 8192);
    stageH(BgH0, lBb);
    stageH(BgH1, lBb + 8192);
    stageH(Ag0 + 64, lAb + 16384);
    stageH(BgH0 + 64, lBb + 16384);
    stageH(BgH1 + 64, lBb + 16384 + 8192);
  }
  VMCNT(6);   // tile0's 8 loads retired; tile1's 3 stageH (6 loads) in flight
  __builtin_amdgcn_s_barrier();

  const unsigned short* lA0 = lAb;
  const unsigned short* lB0 = lBb;
  const unsigned short* lA1 = lAb + 16384;
  const unsigned short* lB1 = lBb + 16384;

  for (int sub = 0; sub < NSUB; ++sub) {
    const int brow = brow0 + sub;
    const unsigned short* Ag   = A + (size_t)brow * 256 * K;
    const unsigned short* AgH1 = Ag + (size_t)128 * K;
    const int nbrow = (sub + 1 < NSUB) ? brow + 1 : brow;  // last sub: self (unread)
    const unsigned short* AgN   = A + (size_t)nbrow * 256 * K;
    const unsigned short* AgNH1 = AgN + (size_t)128 * K;

    for (int it = 0; it < NI; ++it) {
      const int t = it << 1;
      const size_t kT1 = (size_t)(t + 1) * 64;
      const bool o2 = (t + 2 >= NT);
      const bool o3 = (t + 3 >= NT);
      const size_t k2 = (size_t)((t + 2) & NTm) * 64;
      const size_t k3 = (size_t)((t + 3) & NTm) * 64;
      const unsigned short* A0s2 = (o2 ? AgN : Ag) + k2;     // A.H0(t+2)
      const unsigned short* A1s2 = (o2 ? AgNH1 : AgH1) + k2; // A.H1(t+2)
      const unsigned short* A0s3 = (o3 ? AgN : Ag) + k3;     // A.H0(t+3)

      // ---- ph1: rd (12) | stage A.H1(t+1) | lgkm(8) | Q1
      RD_PH1(lA0, lB0);
      stageH(AgH1 + kT1, lAb + 16384 + 8192);
      asm volatile("s_waitcnt lgkmcnt(8)" ::: "memory");
      PH_MFMA_Q(1);
      __builtin_amdgcn_s_barrier();

      // ---- ph2: rd (4) | Q2
      RD_PH2(lB0);
      PH_MFMA_Q(2);
      __builtin_amdgcn_s_barrier();

      // ---- ph3: rd (8) | stage B.H0(t+2, wrap-in-panel) | Q3
      RD_PH3(lA0, lB0);
      stageH(BgH0 + k2, lBb);
      PH_MFMA_Q(3);
      __builtin_amdgcn_s_barrier();

      // ---- ph4: stage B.H1(t+2), A.H0(t+2) | Q4 | vmcnt(6)
      stageH(BgH1 + k2, lBb + 8192);
      stageH(A0s2, lAb);
      PH_MFMA_Q(4);
      VMCNT(6);
      __builtin_amdgcn_s_barrier();

      // ---- ph5: rd t+1 (12) | stage A.H1(t+2) | lgkm(8) | Q1
      RD_PH1(lA1, lB1);
      stageH(A1s2, lAb + 8192);
      asm volatile("s_waitcnt lgkmcnt(8)" ::: "memory");
      PH_MFMA_Q(1);
      __builtin_amdgcn_s_barrier();

      // ---- ph6: rd t+1 (4) | Q2
      RD_PH2(lB1);
      PH_MFMA_Q(2);
      __builtin_amdgcn_s_barrier();

      // ---- ph7: rd t+1 (8) | stage B.H0(t+3) | Q3
      RD_PH3(lA1, lB1);
      stageH(BgH0 + k3, lBb + 16384);
      PH_MFMA_Q(3);
      __builtin_amdgcn_s_barrier();

      // ---- ph8: stage B.H1(t+3), A.H0(t+3) | Q4 | vmcnt(6)
      stageH(BgH1 + k3, lBb + 16384 + 8192);
      stageH(A0s3, lAb + 16384);
      PH_MFMA_Q(4);
      VMCNT(6);
      __builtin_amdgcn_s_barrier();
    }

    // ---- per-sub epilogue (no LDS, no barriers; stores age into vmcnt queue as
    //      OLDER entries -> later counted waits only get stricter) ----
    if constexpr (EPI == 3) {
      const int row0 = brow * 256 + wrow * 64 + lk * 4;
      const int col0 = bcol * 128 + wcol * 64 + lr;
#pragma unroll
      for (int m = 0; m < 4; ++m)
#pragma unroll
        for (int n = 0; n < 4; ++n)
#pragma unroll
          for (int j = 0; j < 4; ++j) {
            float g = acc[m][n][j];       // gate
            float u = acc[m + 4][n][j];   // up
            float s = g / (1.0f + __expf(-g));  // silu
            ((unsigned short*)Cout)[(size_t)(row0 + m * 16 + j) * N + (col0 + n * 16)] =
                f2bf_rne(s * u);
          }
      if (sub + 1 < NSUB) {
#pragma unroll
        for (int m = 0; m < 8; ++m)
#pragma unroll
          for (int n = 0; n < 4; ++n)
            acc[m][n] = f32x4{0.f, 0.f, 0.f, 0.f};
      }
    } else {
      const int row0 = brow * 256 + wr * 128 + lk * 4;
      const int col0 = bcol * 256 + wc * 64 + lr;
#pragma unroll
      for (int m = 0; m < 8; ++m)
#pragma unroll
        for (int n = 0; n < 4; ++n)
#pragma unroll
          for (int j = 0; j < 4; ++j) {
            size_t idx = (size_t)(row0 + m * 16 + j) * N + (col0 + n * 16);
            ((float*)Cout)[idx] = acc[m][n][j];
          }
    }
  }
  VMCNT(0);  // drain trailing (unread) tail stages before exit

#undef RD_PH1
#undef RD_PH2
#undef RD_PH3
#undef PH_CORE_BEGIN
#undef PH_CORE_END
#undef MF
#undef PH_MFMA_Q
}

extern "C" void kernel_launch(void* const* d_in, const int* in_sizes, int n_in,
                              void* d_out, int out_size, void* d_ws, size_t ws_size,
                              hipStream_t stream) {
  const float* x  = (const float*)d_in[0];
  const float* w1 = (const float*)d_in[1];
  const float* w2 = (const float*)d_in[2];
  const float* w3 = (const float*)d_in[3];
  float* out = (float*)d_out;

  const int M = M_ROWS, E = E_DIM, H = H_DIM;

  // ws layout (bf16 elements):
  //   [0, 32MB)   xb    | [32, 64MB) w1b | [64, 96MB) w2b | [96, 224MB) h
  //   w3b: [224, 256MB) if ws_size permits (hoisted cvt), else aliases xb (late cvt).
  unsigned short* xb  = (unsigned short*)d_ws;
  unsigned short* w1b = xb + (size_t)M * E;
  unsigned short* w2b = w1b + (size_t)H * E;
  unsigned short* hb  = w2b + (size_t)H * E;

  const int n8 = (M * E) / 8;  // == (H*E)/8 == (E*H)/8 == 2097152
  const size_t need_hoist = ((size_t)M * E + 2 * (size_t)H * E + (size_t)M * H + (size_t)E * H) * 2;

  if (ws_size >= need_hoist) {
    unsigned short* w3b = hb + (size_t)M * H;  // dedicated region
    cvt4_f32_bf16<<<dim3(n8 / 256, 4), 256, 0, stream>>>(x, xb, w1, w1b, w2, w2b, w3, w3b, n8);
    gemm256<3><<<dim3(1024), 512, 0, stream>>>(xb, w1b, w2b, hb, M, H, E);
    gemm256<0><<<dim3(E / 256, M / 256), 512, 0, stream>>>(hb, w3b, nullptr, out, M, E, H);
  } else {
    unsigned short* w3b = xb;  // safe: cvt(w3) is stream-ordered after fused GEMM reads xb
    cvt4_f32_bf16<<<dim3(n8 / 256, 3), 256, 0, stream>>>(x, xb, w1, w1b, w2, w2b, nullptr, nullptr, n8);
    gemm256<3><<<dim3(1024), 512, 0, stream>>>(xb, w1b, w2b, hb, M, H, E);
    cvt4_f32_bf16<<<dim3(n8 / 256, 1), 256, 0, stream>>>(w3, w3b, nullptr, nullptr, nullptr, nullptr, nullptr, nullptr, n8);
    gemm256<0><<<dim3(E / 256, M / 256), 512, 0, stream>>>(hb, w3b, nullptr, out, M, E, H);
  }
}

// Round 20
// 739.611 us; speedup vs baseline: 1.0595x; 1.0200x over previous
//
#include <hip/hip_runtime.h>
#include <hip/hip_bf16.h>

// Problem dims (fixed by reference): x[B*S=8192, E=2048], w1/w2[H=8192, E], w3[E, H]
#define M_ROWS 8192
#define E_DIM  2048
#define H_DIM  8192

typedef __attribute__((ext_vector_type(8))) short bf16x8;
typedef __attribute__((ext_vector_type(4))) float f32x4;
typedef __attribute__((ext_vector_type(4))) unsigned int uint4v;

__device__ __forceinline__ unsigned short f2bf_rne(float x) {
  unsigned u = __builtin_bit_cast(unsigned, x);
  u += 0x7FFFu + ((u >> 16) & 1u);
  return (unsigned short)(u >> 16);
}

// ---------------- fp32 -> bf16 conversion, up to 4 segments per launch ----------------
__global__ __launch_bounds__(256) void cvt4_f32_bf16(const float* __restrict__ s0, unsigned short* __restrict__ d0,
                                                     const float* __restrict__ s1, unsigned short* __restrict__ d1,
                                                     const float* __restrict__ s2, unsigned short* __restrict__ d2,
                                                     const float* __restrict__ s3, unsigned short* __restrict__ d3,
                                                     int n8) {
  int i = blockIdx.x * blockDim.x + threadIdx.x;
  if (i >= n8) return;
  const float* in = (blockIdx.y == 0) ? s0 : (blockIdx.y == 1) ? s1 : (blockIdx.y == 2) ? s2 : s3;
  unsigned short* out = (blockIdx.y == 0) ? d0 : (blockIdx.y == 1) ? d1 : (blockIdx.y == 2) ? d2 : d3;
  const float4* p = (const float4*)(in + (size_t)i * 8);
  float4 a = p[0];
  float4 b = p[1];
  union { unsigned short us[8]; uint4v v; } r;
  r.us[0] = f2bf_rne(a.x); r.us[1] = f2bf_rne(a.y);
  r.us[2] = f2bf_rne(a.z); r.us[3] = f2bf_rne(a.w);
  r.us[4] = f2bf_rne(b.x); r.us[5] = f2bf_rne(b.y);
  r.us[6] = f2bf_rne(b.z); r.us[7] = f2bf_rne(b.w);
  *(uint4v*)(out + (size_t)i * 8) = r.v;
}

// ---------------- async global -> LDS, 16B per lane ----------------
__device__ __forceinline__ void gld_lds16(const unsigned short* g, unsigned short* l) {
  __builtin_amdgcn_global_load_lds(
      (const __attribute__((address_space(1))) unsigned int*)g,
      (__attribute__((address_space(3))) unsigned int*)l, 16, 0, 0);
}

#define VMCNT(n)   asm volatile("s_waitcnt vmcnt(" #n ")" ::: "memory")

// ====== 256-row 8-phase/2-K-tile GEMM (m201 cadence; R19 schedule + NSUB=8 BROW-SWEEP) ======
// 512 threads, BK=64, buf0=even buf1=odd K-tiles, 128KiB flat LDS, XOR-swizzled LDS
// reads via pre-swizzled global source, setprio on MFMA, vmcnt(6) at ph4/ph8, lgkm(8)
// hint on 12-read phases. Stage dests + timing + vmcnt ledger = R12/R16-verified;
// only stage SOURCES roll across subs (R17/R19-validated mechanism).
// EPI=0 (down-proj): 8 waves 2Mx4N, 256x256 tile, fp32 store, generic XCD swizzle, NSUB=1.
// EPI=3 (fused gate+up): 8 waves 4Mx2N, wave-local silu epilogue (R16: MfmaUtil 47).
//   NSUB=8 BROW-SWEEP: grid 256 (1 round/CU); bcol = xcd*8+(idx&7) FIXED per block
//   (w1/w2 panels L2-hot across all subs; tail B-stages wrap k in-panel);
//   brow = (idx>>3)*8+sub (only A sources redirect at sub boundary). Concurrent
//   per-XCD working set == R16/R19's (8 B-panels + 4 active A-panels, lockstep
//   brow-groups) — R19 measured FETCH 398MB (no R17-style A-thrash). Removes ALL
//   round boundaries (R19: 4 rounds -> 1).
template <int EPI>
__global__ __launch_bounds__(512, 2)
void gemm256(const unsigned short* __restrict__ A,
             const unsigned short* __restrict__ B,
             const unsigned short* __restrict__ B2,
             void* __restrict__ Cout,
             int M, int N, int K) {
  __shared__ unsigned short sh[65536];     // 128KiB: [0,32768)=lA dbuf, [32768,65536)=lB dbuf
  unsigned short* lAb = sh;                // lA[parity] = lAb + parity*16384
  unsigned short* lBb = sh + 32768;        // lB[parity] = lBb + parity*16384

  const int tid = threadIdx.x;
  const int lane = tid & 63;
  const int wave = tid >> 6;
  const int wr = wave >> 2;   // EPI0: 0..1 (128 rows each)
  const int wc = wave & 3;    // EPI0: 0..3 (64 cols each)
  const int wrow = wave >> 1; // EPI3: 0..3 (64 rows each)
  const int wcol = wave & 1;  // EPI3: 0..1 (64 cols each)
  const int lr = lane & 15, lk = lane >> 4;

  const int gx = gridDim.x;
  const int wg = blockIdx.y * gx + blockIdx.x;
  const int NSUB = (EPI == 3) ? 8 : 1;
  int bcol, brow0;
  if constexpr (EPI == 3) {
    // brow-sweep mapping (bijective over 256 blocks x 8 subs = 2048 tiles)
    const int xcd = wg & 7, idx = wg >> 3;
    bcol = xcd * 8 + (idx & 7);       // 0..63, FIXED per block
    brow0 = (idx >> 3) * 8;           // block sweeps brow0..brow0+7
  } else {
    // generic bijective XCD swizzle (nwg % 8 == 0)
    const int nwg = gx * gridDim.y;
    const int swz = (wg & 7) * (nwg >> 3) + (wg >> 3);
    bcol = swz % gx;
    brow0 = swz / gx;
  }

  const unsigned short* BgH0;  // source for B-LDS rows 0-127 (fixed per block)
  const unsigned short* BgH1;  // source for B-LDS rows 128-255
  if constexpr (EPI == 3) {
    BgH0 = B  + (size_t)bcol * 128 * K;   // w1 panel
    BgH1 = B2 + (size_t)bcol * 128 * K;   // w2 panel
  } else {
    BgH0 = B + (size_t)bcol * 256 * K;
    BgH1 = BgH0 + (size_t)128 * K;
  }

  f32x4 acc[8][4] = {};
  const int NT = K >> 6;        // 32 (fused) / 128 (down); power of 2
  const int NI = NT >> 1;
  const int NTm = NT - 1;

  // stage one 128x64 half-tile: linear LDS dest (lane*16B), inverse-swizzled global src
  auto stageH = [&](const unsigned short* gbase, unsigned short* ldsh) {
#pragma unroll
    for (int i = 0; i < 2; ++i) {
      int p = i * 4096 + tid * 8;               // physical element offset in half
      int row = p >> 6;                          // 0..127
      int lslot = ((p >> 3) & 7) ^ (row & 7);    // logical 8-elem slot
      gld_lds16(gbase + (size_t)row * K + lslot * 8, ldsh + p);
    }
  };

  const int xsw = (lr & 7) << 3;  // read-side swizzle XOR (element units)
  bf16x8 af[8][2], bf[4][2], bu[4][2];  // EPI3: af[0-3], bf=w1 frags, bu=w2 frags

#define RD_PH1(LA, LB) \
  if constexpr (EPI == 3) { \
    _Pragma("unroll") for (int m = 0; m < 4; ++m) { \
      int r = wrow * 64 + m * 16 + lr; \
      af[m][0] = *(const bf16x8*)&LA[(r * 64 + lk * 8) ^ xsw]; \
      af[m][1] = *(const bf16x8*)&LA[(r * 64 + 32 + lk * 8) ^ xsw]; } \
    _Pragma("unroll") for (int n = 0; n < 2; ++n) { \
      int r = wcol * 64 + n * 16 + lr; \
      bf[n][0] = *(const bf16x8*)&LB[(r * 64 + lk * 8) ^ xsw]; \
      bf[n][1] = *(const bf16x8*)&LB[(r * 64 + 32 + lk * 8) ^ xsw]; } \
  } else { \
    _Pragma("unroll") for (int m = 0; m < 4; ++m) { \
      int r = wr * 128 + m * 16 + lr; \
      af[m][0] = *(const bf16x8*)&LA[(r * 64 + lk * 8) ^ xsw]; \
      af[m][1] = *(const bf16x8*)&LA[(r * 64 + 32 + lk * 8) ^ xsw]; } \
    _Pragma("unroll") for (int n = 0; n < 2; ++n) { \
      int r = wc * 64 + n * 16 + lr; \
      bf[n][0] = *(const bf16x8*)&LB[(r * 64 + lk * 8) ^ xsw]; \
      bf[n][1] = *(const bf16x8*)&LB[(r * 64 + 32 + lk * 8) ^ xsw]; } \
  }
#define RD_PH2(LB) \
  { \
    const int wcx = (EPI == 3) ? wcol : wc; \
    _Pragma("unroll") for (int n = 2; n < 4; ++n) { \
      int r = wcx * 64 + n * 16 + lr; \
      bf[n][0] = *(const bf16x8*)&LB[(r * 64 + lk * 8) ^ xsw]; \
      bf[n][1] = *(const bf16x8*)&LB[(r * 64 + 32 + lk * 8) ^ xsw]; } \
  }
#define RD_PH3(LA, LB) \
  if constexpr (EPI == 3) { \
    _Pragma("unroll") for (int n = 0; n < 4; ++n) { \
      int r = wcol * 64 + n * 16 + lr; \
      bu[n][0] = *(const bf16x8*)&LB[8192 + ((r * 64 + lk * 8) ^ xsw)]; \
      bu[n][1] = *(const bf16x8*)&LB[8192 + ((r * 64 + 32 + lk * 8) ^ xsw)]; } \
  } else { \
    _Pragma("unroll") for (int m = 4; m < 8; ++m) { \
      int r = wr * 128 + m * 16 + lr; \
      af[m][0] = *(const bf16x8*)&LA[(r * 64 + lk * 8) ^ xsw]; \
      af[m][1] = *(const bf16x8*)&LA[(r * 64 + 32 + lk * 8) ^ xsw]; } \
  }
#define PH_CORE_BEGIN \
  __builtin_amdgcn_s_barrier(); \
  asm volatile("s_waitcnt lgkmcnt(0)" ::: "memory"); \
  __builtin_amdgcn_sched_barrier(0); \
  __builtin_amdgcn_s_setprio(1);
#define PH_CORE_END __builtin_amdgcn_s_setprio(0);
#define MF(ACC_M, AV, BV) \
  acc[ACC_M][n] = __builtin_amdgcn_mfma_f32_16x16x32_bf16(AV[ks], BV[ks], acc[ACC_M][n], 0, 0, 0);
#define PH_MFMA_Q(Q) \
  PH_CORE_BEGIN \
  if constexpr (EPI == 3) { \
    if constexpr (Q == 1) { _Pragma("unroll") for (int m = 0; m < 4; ++m) _Pragma("unroll") for (int n = 0; n < 2; ++n) _Pragma("unroll") for (int ks = 0; ks < 2; ++ks) MF(m, af[m], bf[n]) } \
    if constexpr (Q == 2) { _Pragma("unroll") for (int m = 0; m < 4; ++m) _Pragma("unroll") for (int n = 2; n < 4; ++n) _Pragma("unroll") for (int ks = 0; ks < 2; ++ks) MF(m, af[m], bf[n]) } \
    if constexpr (Q == 3) { _Pragma("unroll") for (int m = 0; m < 4; ++m) _Pragma("unroll") for (int n = 0; n < 2; ++n) _Pragma("unroll") for (int ks = 0; ks < 2; ++ks) MF(m + 4, af[m], bu[n]) } \
    if constexpr (Q == 4) { _Pragma("unroll") for (int m = 0; m < 4; ++m) _Pragma("unroll") for (int n = 2; n < 4; ++n) _Pragma("unroll") for (int ks = 0; ks < 2; ++ks) MF(m + 4, af[m], bu[n]) } \
  } else { \
    if constexpr (Q == 1) { _Pragma("unroll") for (int m = 0; m < 4; ++m) _Pragma("unroll") for (int n = 0; n < 2; ++n) _Pragma("unroll") for (int ks = 0; ks < 2; ++ks) MF(m, af[m], bf[n]) } \
    if constexpr (Q == 2) { _Pragma("unroll") for (int m = 0; m < 4; ++m) _Pragma("unroll") for (int n = 2; n < 4; ++n) _Pragma("unroll") for (int ks = 0; ks < 2; ++ks) MF(m, af[m], bf[n]) } \
    if constexpr (Q == 3) { _Pragma("unroll") for (int m = 4; m < 8; ++m) _Pragma("unroll") for (int n = 0; n < 2; ++n) _Pragma("unroll") for (int ks = 0; ks < 2; ++ks) MF(m, af[m], bf[n]) } \
    if constexpr (Q == 4) { _Pragma("unroll") for (int m = 4; m < 8; ++m) _Pragma("unroll") for (int n = 2; n < 4; ++n) _Pragma("unroll") for (int ks = 0; ks < 2; ++ks) MF(m, af[m], bf[n]) } \
  } \
  PH_CORE_END

  // ---- prologue (R17/R19-validated): tile0 {A.H0,A.H1,B.H0,B.H1} + tile1
  //      {A.H0,B.H0,B.H1}; vmcnt(6); tile1.A.H1 staged at it0-ph1 (unconditional) ----
  {
    const unsigned short* Ag0  = A + (size_t)brow0 * 256 * K;
    const unsigned short* Ag0H = Ag0 + (size_t)128 * K;
    stageH(Ag0, lAb);
    stageH(Ag0H, lAb + 8192);
    stageH(BgH0, lBb);
    stageH(BgH1, lBb + 8192);
    stageH(Ag0 + 64, lAb + 16384);
    stageH(BgH0 + 64, lBb + 16384);
    stageH(BgH1 + 64, lBb + 16384 + 8192);
  }
  VMCNT(6);   // tile0's 8 loads retired; tile1's 3 stageH (6 loads) in flight
  __builtin_amdgcn_s_barrier();

  const unsigned short* lA0 = lAb;
  const unsigned short* lB0 = lBb;
  const unsigned short* lA1 = lAb + 16384;
  const unsigned short* lB1 = lBb + 16384;

  for (int sub = 0; sub < NSUB; ++sub) {
    const int brow = brow0 + sub;
    const unsigned short* Ag   = A + (size_t)brow * 256 * K;
    const unsigned short* AgH1 = Ag + (size_t)128 * K;
    const int nbrow = (sub + 1 < NSUB) ? brow + 1 : brow;  // last sub: self (unread)
    const unsigned short* AgN   = A + (size_t)nbrow * 256 * K;
    const unsigned short* AgNH1 = AgN + (size_t)128 * K;

    for (int it = 0; it < NI; ++it) {
      const int t = it << 1;
      const size_t kT1 = (size_t)(t + 1) * 64;
      const bool o2 = (t + 2 >= NT);
      const bool o3 = (t + 3 >= NT);
      const size_t k2 = (size_t)((t + 2) & NTm) * 64;
      const size_t k3 = (size_t)((t + 3) & NTm) * 64;
      const unsigned short* A0s2 = (o2 ? AgN : Ag) + k2;     // A.H0(t+2)
      const unsigned short* A1s2 = (o2 ? AgNH1 : AgH1) + k2; // A.H1(t+2)
      const unsigned short* A0s3 = (o3 ? AgN : Ag) + k3;     // A.H0(t+3)

      // ---- ph1: rd (12) | stage A.H1(t+1) | lgkm(8) | Q1
      RD_PH1(lA0, lB0);
      stageH(AgH1 + kT1, lAb + 16384 + 8192);
      asm volatile("s_waitcnt lgkmcnt(8)" ::: "memory");
      PH_MFMA_Q(1);
      __builtin_amdgcn_s_barrier();

      // ---- ph2: rd (4) | Q2
      RD_PH2(lB0);
      PH_MFMA_Q(2);
      __builtin_amdgcn_s_barrier();

      // ---- ph3: rd (8) | stage B.H0(t+2, wrap-in-panel) | Q3
      RD_PH3(lA0, lB0);
      stageH(BgH0 + k2, lBb);
      PH_MFMA_Q(3);
      __builtin_amdgcn_s_barrier();

      // ---- ph4: stage B.H1(t+2), A.H0(t+2) | Q4 | vmcnt(6)
      stageH(BgH1 + k2, lBb + 8192);
      stageH(A0s2, lAb);
      PH_MFMA_Q(4);
      VMCNT(6);
      __builtin_amdgcn_s_barrier();

      // ---- ph5: rd t+1 (12) | stage A.H1(t+2) | lgkm(8) | Q1
      RD_PH1(lA1, lB1);
      stageH(A1s2, lAb + 8192);
      asm volatile("s_waitcnt lgkmcnt(8)" ::: "memory");
      PH_MFMA_Q(1);
      __builtin_amdgcn_s_barrier();

      // ---- ph6: rd t+1 (4) | Q2
      RD_PH2(lB1);
      PH_MFMA_Q(2);
      __builtin_amdgcn_s_barrier();

      // ---- ph7: rd t+1 (8) | stage B.H0(t+3) | Q3
      RD_PH3(lA1, lB1);
      stageH(BgH0 + k3, lBb + 16384);
      PH_MFMA_Q(3);
      __builtin_amdgcn_s_barrier();

      // ---- ph8: stage B.H1(t+3), A.H0(t+3) | Q4 | vmcnt(6)
      stageH(BgH1 + k3, lBb + 16384 + 8192);
      stageH(A0s3, lAb + 16384);
      PH_MFMA_Q(4);
      VMCNT(6);
      __builtin_amdgcn_s_barrier();
    }

    // ---- per-sub epilogue (no LDS, no barriers; stores age into vmcnt queue as
    //      OLDER entries -> later counted waits only get stricter) ----
    if constexpr (EPI == 3) {
      const int row0 = brow * 256 + wrow * 64 + lk * 4;
      const int col0 = bcol * 128 + wcol * 64 + lr;
#pragma unroll
      for (int m = 0; m < 4; ++m)
#pragma unroll
        for (int n = 0; n < 4; ++n)
#pragma unroll
          for (int j = 0; j < 4; ++j) {
            float g = acc[m][n][j];       // gate
            float u = acc[m + 4][n][j];   // up
            float s = g / (1.0f + __expf(-g));  // silu
            ((unsigned short*)Cout)[(size_t)(row0 + m * 16 + j) * N + (col0 + n * 16)] =
                f2bf_rne(s * u);
          }
      if (sub + 1 < NSUB) {
#pragma unroll
        for (int m = 0; m < 8; ++m)
#pragma unroll
          for (int n = 0; n < 4; ++n)
            acc[m][n] = f32x4{0.f, 0.f, 0.f, 0.f};
      }
    } else {
      const int row0 = brow * 256 + wr * 128 + lk * 4;
      const int col0 = bcol * 256 + wc * 64 + lr;
#pragma unroll
      for (int m = 0; m < 8; ++m)
#pragma unroll
        for (int n = 0; n < 4; ++n)
#pragma unroll
          for (int j = 0; j < 4; ++j) {
            size_t idx = (size_t)(row0 + m * 16 + j) * N + (col0 + n * 16);
            ((float*)Cout)[idx] = acc[m][n][j];
          }
    }
  }
  VMCNT(0);  // drain trailing (unread) tail stages before exit

#undef RD_PH1
#undef RD_PH2
#undef RD_PH3
#undef PH_CORE_BEGIN
#undef PH_CORE_END
#undef MF
#undef PH_MFMA_Q
}

extern "C" void kernel_launch(void* const* d_in, const int* in_sizes, int n_in,
                              void* d_out, int out_size, void* d_ws, size_t ws_size,
                              hipStream_t stream) {
  const float* x  = (const float*)d_in[0];
  const float* w1 = (const float*)d_in[1];
  const float* w2 = (const float*)d_in[2];
  const float* w3 = (const float*)d_in[3];
  float* out = (float*)d_out;

  const int M = M_ROWS, E = E_DIM, H = H_DIM;

  // ws layout (bf16 elements):
  //   [0, 32MB)   xb    | [32, 64MB) w1b | [64, 96MB) w2b | [96, 224MB) h
  //   w3b: [224, 256MB) if ws_size permits (hoisted cvt), else aliases xb (late cvt).
  unsigned short* xb  = (unsigned short*)d_ws;
  unsigned short* w1b = xb + (size_t)M * E;
  unsigned short* w2b = w1b + (size_t)H * E;
  unsigned short* hb  = w2b + (size_t)H * E;

  const int n8 = (M * E) / 8;  // == (H*E)/8 == (E*H)/8 == 2097152
  const size_t need_hoist = ((size_t)M * E + 2 * (size_t)H * E + (size_t)M * H + (size_t)E * H) * 2;

  if (ws_size >= need_hoist) {
    unsigned short* w3b = hb + (size_t)M * H;  // dedicated region
    cvt4_f32_bf16<<<dim3(n8 / 256, 4), 256, 0, stream>>>(x, xb, w1, w1b, w2, w2b, w3, w3b, n8);
    gemm256<3><<<dim3(256), 512, 0, stream>>>(xb, w1b, w2b, hb, M, H, E);
    gemm256<0><<<dim3(E / 256, M / 256), 512, 0, stream>>>(hb, w3b, nullptr, out, M, E, H);
  } else {
    unsigned short* w3b = xb;  // safe: cvt(w3) is stream-ordered after fused GEMM reads xb
    cvt4_f32_bf16<<<dim3(n8 / 256, 3), 256, 0, stream>>>(x, xb, w1, w1b, w2, w2b, nullptr, nullptr, n8);
    gemm256<3><<<dim3(256), 512, 0, stream>>>(xb, w1b, w2b, hb, M, H, E);
    cvt4_f32_bf16<<<dim3(n8 / 256, 1), 256, 0, stream>>>(w3, w3b, nullptr, nullptr, nullptr, nullptr, nullptr, nullptr, n8);
    gemm256<0><<<dim3(E / 256, M / 256), 512, 0, stream>>>(hb, w3b, nullptr, out, M, E, H);
  }
}